// Round 17
// baseline (172.493 us; speedup 1.0000x reference)
//
#include <hip/hip_runtime.h>

#define T_DIM 512
#define I_DIM 16
#define B_DIM 4096
#define K_CH 16            // steps per chunk (ring = 32 KB -> 4 blocks/CU)
#define COLS 4             // real batch cols per block (16-wide tile, 4x dup)

typedef _Float16 f16x8 __attribute__((ext_vector_type(8)));
typedef float f32x4 __attribute__((ext_vector_type(4)));
typedef __fp16 hf2v __attribute__((ext_vector_type(2)));

union Frag { f16x8 v; __fp16 e[8]; uint4 u; };

__device__ __forceinline__ float fast_tanh(float x) {
    float e = __builtin_amdgcn_exp2f(x * 2.885390081777927f);
    return 1.0f - 2.0f * __builtin_amdgcn_rcpf(e + 1.0f);
}

__device__ __forceinline__ f16x8 pack8(float a0, float a1, float a2, float a3,
                                       float b0, float b1, float b2, float b3) {
    Frag f;
    hf2v p0 = __builtin_amdgcn_cvt_pkrtz(a0, a1);
    hf2v p1 = __builtin_amdgcn_cvt_pkrtz(a2, a3);
    hf2v p2 = __builtin_amdgcn_cvt_pkrtz(b0, b1);
    hf2v p3 = __builtin_amdgcn_cvt_pkrtz(b2, b3);
    f.e[0] = p0[0]; f.e[1] = p0[1]; f.e[2] = p1[0]; f.e[3] = p1[1];
    f.e[4] = p2[0]; f.e[5] = p2[1]; f.e[6] = p3[0]; f.e[7] = p3[1];
    return f.v;
}
__device__ __forceinline__ f16x8 tanhpack(f32x4 a, f32x4 b) {
    return pack8(fast_tanh(a[0]), fast_tanh(a[1]), fast_tanh(a[2]), fast_tanh(a[3]),
                 fast_tanh(b[0]), fast_tanh(b[1]), fast_tanh(b[2]), fast_tanh(b[3]));
}
// q-permuted A-frag loads (q(8g+j) = 4g+j | 16+4g+j-4), verified r15/r16
__device__ __forceinline__ f16x8 loadWq32(const float* W, int row, int g) {
    float4 a = *reinterpret_cast<const float4*>(W + row * 32 + 4 * g);
    float4 b = *reinterpret_cast<const float4*>(W + row * 32 + 16 + 4 * g);
    return pack8(a.x, a.y, a.z, a.w, b.x, b.y, b.z, b.w);
}
__device__ __forceinline__ f16x8 loadWq16(const float* W, int row, int g) {
    float4 a = *reinterpret_cast<const float4*>(W + row * 16 + 4 * g);
    return pack8(a.x, a.y, a.z, a.w, 0.f, 0.f, 0.f, 0.f);
}

// r16 producer-consumer structure, occupancy-doubled: 4 real cols/block,
// 1024 two-wave blocks = 8 waves/CU = 2/SIMD; K_CH=16 ring (32 KB).
__global__ void __launch_bounds__(128)
rnn2_pc4_kernel(const float* __restrict__ x,
                const float* __restrict__ Wih0, const float* __restrict__ Whh0,
                const float* __restrict__ bih0, const float* __restrict__ bhh0,
                const float* __restrict__ Wih1, const float* __restrict__ Whh1,
                const float* __restrict__ bih1, const float* __restrict__ bhh1,
                const float* __restrict__ fcw, const float* __restrict__ fcb,
                float* __restrict__ out)
{
    const int tid = threadIdx.x;
    const int l   = tid & 63;
    const int wid = tid >> 6;
    const int c   = l & 15;
    const int g   = l >> 4;
    const int rowbase = blockIdx.x * COLS;

    __shared__ __fp16 ring[2][K_CH][64][8];   // 32 KB

    f16x8 wT0[2], wT1[2];
    f32x4 bC[2];
    Frag  h1f;
    f32x4 Xacc[2], L1pre[2];
    float4 xpA, xpB;
    const float* xlane = nullptr;
    float h20=0.f,h21=0.f,h22=0.f,h23=0.f,h24=0.f,h25=0.f,h26=0.f,h27=0.f;

    if (wid == 0) {
#pragma unroll
        for (int tt = 0; tt < 2; ++tt) {
            const int row = c + 16 * tt;
            wT0[tt] = loadWq32(Whh0, row, g);
            wT1[tt] = loadWq16(Wih0, row, g);
            const int r0 = 4 * g + 16 * tt;
            float4 bi = *reinterpret_cast<const float4*>(bih0 + r0);
            float4 bh = *reinterpret_cast<const float4*>(bhh0 + r0);
            bC[tt][0] = bi.x + bh.x; bC[tt][1] = bi.y + bh.y;
            bC[tt][2] = bi.z + bh.z; bC[tt][3] = bi.w + bh.w;
        }
        const size_t xcol = rowbase + (c & (COLS - 1));
        xlane = x + xcol * (size_t)(T_DIM * I_DIM) + 4 * g;
    } else {
#pragma unroll
        for (int tt = 0; tt < 2; ++tt) {
            const int row = c + 16 * tt;
            wT0[tt] = loadWq32(Wih1, row, g);
            wT1[tt] = loadWq32(Whh1, row, g);
            const int r0 = 4 * g + 16 * tt;
            float4 bi = *reinterpret_cast<const float4*>(bih1 + r0);
            float4 bh = *reinterpret_cast<const float4*>(bhh1 + r0);
            bC[tt][0] = bi.x + bh.x; bC[tt][1] = bi.y + bh.y;
            bC[tt][2] = bi.z + bh.z; bC[tt][3] = bi.w + bh.w;
        }
        L1pre[0] = bC[0];      // h2(-1) = 0
        L1pre[1] = bC[1];
    }

#define PSTEP(t, P)                                                                         \
    {                                                                                       \
        f32x4 D0a = __builtin_amdgcn_mfma_f32_16x16x32_f16(wT0[0], h1f.v, Xacc[0], 0,0,0);  \
        f32x4 D0b = __builtin_amdgcn_mfma_f32_16x16x32_f16(wT0[1], h1f.v, Xacc[1], 0,0,0);  \
        Frag xf; xf.v = pack8((P).x, (P).y, (P).z, (P).w, 0.f, 0.f, 0.f, 0.f);              \
        const int tn = ((t) + 3 < T_DIM) ? (t) + 3 : (T_DIM - 1);                           \
        (P) = *reinterpret_cast<const float4*>(xlane + (size_t)tn * I_DIM);                 \
        h1f.v = tanhpack(D0a, D0b);                                                         \
        *reinterpret_cast<uint4*>(&ring[((t) / K_CH) & 1][(t) & (K_CH - 1)][l][0]) = h1f.u; \
        Xacc[0] = __builtin_amdgcn_mfma_f32_16x16x32_f16(wT1[0], xf.v, bC[0], 0,0,0);       \
        Xacc[1] = __builtin_amdgcn_mfma_f32_16x16x32_f16(wT1[1], xf.v, bC[1], 0,0,0);       \
    }

#define CSTEP(t)                                                                            \
    {                                                                                       \
        Frag h1B; h1B.u = *reinterpret_cast<const uint4*>(&ring[((t) / K_CH) & 1][(t) & (K_CH - 1)][l][0]); \
        f32x4 D1a = __builtin_amdgcn_mfma_f32_16x16x32_f16(wT0[0], h1B.v, L1pre[0], 0,0,0); \
        f32x4 D1b = __builtin_amdgcn_mfma_f32_16x16x32_f16(wT0[1], h1B.v, L1pre[1], 0,0,0); \
        h20 = fast_tanh(D1a[0]); h21 = fast_tanh(D1a[1]);                                   \
        h22 = fast_tanh(D1a[2]); h23 = fast_tanh(D1a[3]);                                   \
        h24 = fast_tanh(D1b[0]); h25 = fast_tanh(D1b[1]);                                   \
        h26 = fast_tanh(D1b[2]); h27 = fast_tanh(D1b[3]);                                   \
        Frag h2f; h2f.v = pack8(h20, h21, h22, h23, h24, h25, h26, h27);                    \
        L1pre[0] = __builtin_amdgcn_mfma_f32_16x16x32_f16(wT1[0], h2f.v, bC[0], 0,0,0);     \
        L1pre[1] = __builtin_amdgcn_mfma_f32_16x16x32_f16(wT1[1], h2f.v, bC[1], 0,0,0);     \
    }

#pragma unroll 1
    for (int p = 0; p <= T_DIM / K_CH; ++p) {
        if (wid == 0 && p < T_DIM / K_CH) {
            if (p == 0) {
                float4 x0 = *reinterpret_cast<const float4*>(xlane + 0 * I_DIM);
                Frag xf0; xf0.v = pack8(x0.x, x0.y, x0.z, x0.w, 0.f, 0.f, 0.f, 0.f);
                f32x4 Da = __builtin_amdgcn_mfma_f32_16x16x32_f16(wT1[0], xf0.v, bC[0], 0,0,0);
                f32x4 Db = __builtin_amdgcn_mfma_f32_16x16x32_f16(wT1[1], xf0.v, bC[1], 0,0,0);
                h1f.v = tanhpack(Da, Db);
                *reinterpret_cast<uint4*>(&ring[0][0][l][0]) = h1f.u;      // h1(0)
                float4 x1 = *reinterpret_cast<const float4*>(xlane + 1 * I_DIM);
                Frag xf1; xf1.v = pack8(x1.x, x1.y, x1.z, x1.w, 0.f, 0.f, 0.f, 0.f);
                Xacc[0] = __builtin_amdgcn_mfma_f32_16x16x32_f16(wT1[0], xf1.v, bC[0], 0,0,0);
                Xacc[1] = __builtin_amdgcn_mfma_f32_16x16x32_f16(wT1[1], xf1.v, bC[1], 0,0,0);
                // t = 1
                f32x4 D0a = __builtin_amdgcn_mfma_f32_16x16x32_f16(wT0[0], h1f.v, Xacc[0], 0,0,0);
                f32x4 D0b = __builtin_amdgcn_mfma_f32_16x16x32_f16(wT0[1], h1f.v, Xacc[1], 0,0,0);
                float4 x2 = *reinterpret_cast<const float4*>(xlane + 2 * I_DIM);
                h1f.v = tanhpack(D0a, D0b);
                *reinterpret_cast<uint4*>(&ring[0][1][l][0]) = h1f.u;      // h1(1)
                Frag xf2; xf2.v = pack8(x2.x, x2.y, x2.z, x2.w, 0.f, 0.f, 0.f, 0.f);
                Xacc[0] = __builtin_amdgcn_mfma_f32_16x16x32_f16(wT1[0], xf2.v, bC[0], 0,0,0);
                Xacc[1] = __builtin_amdgcn_mfma_f32_16x16x32_f16(wT1[1], xf2.v, bC[1], 0,0,0);
                xpA = *reinterpret_cast<const float4*>(xlane + 3 * I_DIM);
                xpB = *reinterpret_cast<const float4*>(xlane + 4 * I_DIM);
#pragma unroll 2
                for (int s = 2; s < K_CH; s += 2) { PSTEP(s, xpA) PSTEP(s + 1, xpB) }
            } else {
                const int t0 = p * K_CH;
#pragma unroll 2
                for (int s = 0; s < K_CH; s += 2) { PSTEP(t0 + s, xpA) PSTEP(t0 + s + 1, xpB) }
            }
        }
        if (wid == 1 && p >= 1) {
            const int t0 = (p - 1) * K_CH;
#pragma unroll 2
            for (int s = 0; s < K_CH; s += 2) { CSTEP(t0 + s) CSTEP(t0 + s + 1) }
        }
        __syncthreads();
    }
#undef PSTEP
#undef CSTEP

    // ---- FC epilogue from wave1's h2(T-1) registers ----
    if (wid == 1) {
        float4 fw0 = *reinterpret_cast<const float4*>(fcw + 4 * g);
        float4 fw1 = *reinterpret_cast<const float4*>(fcw + 16 + 4 * g);
        float part = fw0.x * h20 + fw0.y * h21 + fw0.z * h22 + fw0.w * h23
                   + fw1.x * h24 + fw1.y * h25 + fw1.z * h26 + fw1.w * h27;
        part += __shfl_xor(part, 16, 64);
        part += __shfl_xor(part, 32, 64);
        if (l < COLS) out[rowbase + l] = part + fcb[0];
    }
}

extern "C" void kernel_launch(void* const* d_in, const int* in_sizes, int n_in,
                              void* d_out, int out_size, void* d_ws, size_t ws_size,
                              hipStream_t stream) {
    const float* x    = (const float*)d_in[0];
    const float* Wih0 = (const float*)d_in[1];
    const float* Whh0 = (const float*)d_in[2];
    const float* bih0 = (const float*)d_in[3];
    const float* bhh0 = (const float*)d_in[4];
    const float* Wih1 = (const float*)d_in[5];
    const float* Whh1 = (const float*)d_in[6];
    const float* bih1 = (const float*)d_in[7];
    const float* bhh1 = (const float*)d_in[8];
    const float* fcw  = (const float*)d_in[9];
    const float* fcb  = (const float*)d_in[10];
    float* out = (float*)d_out;

    dim3 grid(B_DIM / COLS);   // 1024 blocks x 2 waves = 2048 waves = 8/CU
    rnn2_pc4_kernel<<<grid, 128, 0, stream>>>(x, Wih0, Whh0, bih0, bhh0,
                                              Wih1, Whh1, bih1, bhh1,
                                              fcw, fcb, out);
}

// Round 18
// 98.025 us; speedup vs baseline: 1.7597x; 1.7597x over previous
//
#include <hip/hip_runtime.h>

#define T_DIM 512
#define I_DIM 16
#define B_DIM 4096
#define K_CH 32            // steps per chunk (ring = 64 KB, 2 blocks/CU)
#define COLS 8             // real batch cols per block (16-wide tile, 2x dup)
#define SCL 2.885390081777927f   // 2*log2(e), folded into weights/biases

typedef _Float16 f16x8 __attribute__((ext_vector_type(8)));
typedef float f32x4 __attribute__((ext_vector_type(4)));
typedef __fp16 hf2v __attribute__((ext_vector_type(2)));

union Frag { f16x8 v; __fp16 e[8]; uint4 u; };

// pre-activation already scaled by 2*log2(e): tanh = 1 - 2/(exp2(u)+1)
__device__ __forceinline__ float tanh_s(float u) {
    float e = __builtin_amdgcn_exp2f(u);
    return fmaf(-2.f, __builtin_amdgcn_rcpf(e + 1.f), 1.f);
}

__device__ __forceinline__ f16x8 pack8(float a0, float a1, float a2, float a3,
                                       float b0, float b1, float b2, float b3) {
    Frag f;
    hf2v p0 = __builtin_amdgcn_cvt_pkrtz(a0, a1);
    hf2v p1 = __builtin_amdgcn_cvt_pkrtz(a2, a3);
    hf2v p2 = __builtin_amdgcn_cvt_pkrtz(b0, b1);
    hf2v p3 = __builtin_amdgcn_cvt_pkrtz(b2, b3);
    f.e[0] = p0[0]; f.e[1] = p0[1]; f.e[2] = p1[0]; f.e[3] = p1[1];
    f.e[4] = p2[0]; f.e[5] = p2[1]; f.e[6] = p3[0]; f.e[7] = p3[1];
    return f.v;
}
__device__ __forceinline__ f16x8 tanhpack_s(f32x4 a, f32x4 b) {
    return pack8(tanh_s(a[0]), tanh_s(a[1]), tanh_s(a[2]), tanh_s(a[3]),
                 tanh_s(b[0]), tanh_s(b[1]), tanh_s(b[2]), tanh_s(b[3]));
}
// q-permuted A-frag loads (q(8g+j) = 4g+j | 16+4g+j-4), verified r15/r16,
// now with the tanh scale folded in.
__device__ __forceinline__ f16x8 loadWq32s(const float* W, int row, int g) {
    float4 a = *reinterpret_cast<const float4*>(W + row * 32 + 4 * g);
    float4 b = *reinterpret_cast<const float4*>(W + row * 32 + 16 + 4 * g);
    return pack8(a.x*SCL, a.y*SCL, a.z*SCL, a.w*SCL, b.x*SCL, b.y*SCL, b.z*SCL, b.w*SCL);
}
__device__ __forceinline__ f16x8 loadWq16s(const float* W, int row, int g) {
    float4 a = *reinterpret_cast<const float4*>(W + row * 16 + 4 * g);
    return pack8(a.x*SCL, a.y*SCL, a.z*SCL, a.w*SCL, 0.f, 0.f, 0.f, 0.f);
}

// r16 producer-consumer structure + two chain cuts:
//  (1) consumer: pd1 = Wih1*h1 + b1 precomputed off-chain from ring lookahead;
//      chain is ONE mfma (Whh1*h2prev + pd1) + tanh + pack.
//  (2) tanh scale folded into weights: tanh = exp2,add,rcp,fma.
__global__ void __launch_bounds__(128)
rnn2_pc2_kernel(const float* __restrict__ x,
                const float* __restrict__ Wih0, const float* __restrict__ Whh0,
                const float* __restrict__ bih0, const float* __restrict__ bhh0,
                const float* __restrict__ Wih1, const float* __restrict__ Whh1,
                const float* __restrict__ bih1, const float* __restrict__ bhh1,
                const float* __restrict__ fcw, const float* __restrict__ fcb,
                float* __restrict__ out)
{
    const int tid = threadIdx.x;
    const int l   = tid & 63;
    const int wid = tid >> 6;
    const int c   = l & 15;
    const int g   = l >> 4;
    const int rowbase = blockIdx.x * COLS;

    __shared__ __fp16 ring[2][K_CH][64][8];   // 64 KB

    // wave0 (producer): wT0 = Whh0, wT1 = Wih0 (zero-padded); bC = (bih0+bhh0)*SCL
    // wave1 (consumer): wT0 = Wih1, wT1 = Whh1;               bC = (bih1+bhh1)*SCL
    f16x8 wT0[2], wT1[2];
    f32x4 bC[2];
    Frag  h1f;
    f32x4 Xacc[2];
    float4 xpA, xpB;
    const float* xlane = nullptr;
    float h20=0.f,h21=0.f,h22=0.f,h23=0.f,h24=0.f,h25=0.f,h26=0.f,h27=0.f;
    Frag h2f; h2f.u = make_uint4(0u, 0u, 0u, 0u);   // h2(-1) = 0

    if (wid == 0) {
#pragma unroll
        for (int tt = 0; tt < 2; ++tt) {
            const int row = c + 16 * tt;
            wT0[tt] = loadWq32s(Whh0, row, g);
            wT1[tt] = loadWq16s(Wih0, row, g);
            const int r0 = 4 * g + 16 * tt;
            float4 bi = *reinterpret_cast<const float4*>(bih0 + r0);
            float4 bh = *reinterpret_cast<const float4*>(bhh0 + r0);
            bC[tt][0] = (bi.x + bh.x) * SCL; bC[tt][1] = (bi.y + bh.y) * SCL;
            bC[tt][2] = (bi.z + bh.z) * SCL; bC[tt][3] = (bi.w + bh.w) * SCL;
        }
        const size_t xcol = rowbase + (c & (COLS - 1));
        xlane = x + xcol * (size_t)(T_DIM * I_DIM) + 4 * g;
    } else {
#pragma unroll
        for (int tt = 0; tt < 2; ++tt) {
            const int row = c + 16 * tt;
            wT0[tt] = loadWq32s(Wih1, row, g);
            wT1[tt] = loadWq32s(Whh1, row, g);
            const int r0 = 4 * g + 16 * tt;
            float4 bi = *reinterpret_cast<const float4*>(bih1 + r0);
            float4 bh = *reinterpret_cast<const float4*>(bhh1 + r0);
            bC[tt][0] = (bi.x + bh.x) * SCL; bC[tt][1] = (bi.y + bh.y) * SCL;
            bC[tt][2] = (bi.z + bh.z) * SCL; bC[tt][3] = (bi.w + bh.w) * SCL;
        }
    }

#define PSTEP(t, P)                                                                         \
    {                                                                                       \
        f32x4 D0a = __builtin_amdgcn_mfma_f32_16x16x32_f16(wT0[0], h1f.v, Xacc[0], 0,0,0);  \
        f32x4 D0b = __builtin_amdgcn_mfma_f32_16x16x32_f16(wT0[1], h1f.v, Xacc[1], 0,0,0);  \
        Frag xf; xf.v = pack8((P).x, (P).y, (P).z, (P).w, 0.f, 0.f, 0.f, 0.f);              \
        const int tn = ((t) + 3 < T_DIM) ? (t) + 3 : (T_DIM - 1);                           \
        (P) = *reinterpret_cast<const float4*>(xlane + (size_t)tn * I_DIM);                 \
        h1f.v = tanhpack_s(D0a, D0b);                                                       \
        *reinterpret_cast<uint4*>(&ring[((t) / K_CH) & 1][(t) & (K_CH - 1)][l][0]) = h1f.u; \
        Xacc[0] = __builtin_amdgcn_mfma_f32_16x16x32_f16(wT1[0], xf.v, bC[0], 0,0,0);       \
        Xacc[1] = __builtin_amdgcn_mfma_f32_16x16x32_f16(wT1[1], xf.v, bC[1], 0,0,0);       \
    }

#pragma unroll 1
    for (int p = 0; p <= T_DIM / K_CH; ++p) {
        if (wid == 0 && p < T_DIM / K_CH) {
            if (p == 0) {
                float4 x0 = *reinterpret_cast<const float4*>(xlane + 0 * I_DIM);
                Frag xf0; xf0.v = pack8(x0.x, x0.y, x0.z, x0.w, 0.f, 0.f, 0.f, 0.f);
                f32x4 Da = __builtin_amdgcn_mfma_f32_16x16x32_f16(wT1[0], xf0.v, bC[0], 0,0,0);
                f32x4 Db = __builtin_amdgcn_mfma_f32_16x16x32_f16(wT1[1], xf0.v, bC[1], 0,0,0);
                h1f.v = tanhpack_s(Da, Db);
                *reinterpret_cast<uint4*>(&ring[0][0][l][0]) = h1f.u;      // h1(0)
                float4 x1 = *reinterpret_cast<const float4*>(xlane + 1 * I_DIM);
                Frag xf1; xf1.v = pack8(x1.x, x1.y, x1.z, x1.w, 0.f, 0.f, 0.f, 0.f);
                Xacc[0] = __builtin_amdgcn_mfma_f32_16x16x32_f16(wT1[0], xf1.v, bC[0], 0,0,0);
                Xacc[1] = __builtin_amdgcn_mfma_f32_16x16x32_f16(wT1[1], xf1.v, bC[1], 0,0,0);
                // t = 1
                f32x4 D0a = __builtin_amdgcn_mfma_f32_16x16x32_f16(wT0[0], h1f.v, Xacc[0], 0,0,0);
                f32x4 D0b = __builtin_amdgcn_mfma_f32_16x16x32_f16(wT0[1], h1f.v, Xacc[1], 0,0,0);
                float4 x2 = *reinterpret_cast<const float4*>(xlane + 2 * I_DIM);
                h1f.v = tanhpack_s(D0a, D0b);
                *reinterpret_cast<uint4*>(&ring[0][1][l][0]) = h1f.u;      // h1(1)
                Frag xf2; xf2.v = pack8(x2.x, x2.y, x2.z, x2.w, 0.f, 0.f, 0.f, 0.f);
                Xacc[0] = __builtin_amdgcn_mfma_f32_16x16x32_f16(wT1[0], xf2.v, bC[0], 0,0,0);
                Xacc[1] = __builtin_amdgcn_mfma_f32_16x16x32_f16(wT1[1], xf2.v, bC[1], 0,0,0);
                xpA = *reinterpret_cast<const float4*>(xlane + 3 * I_DIM);
                xpB = *reinterpret_cast<const float4*>(xlane + 4 * I_DIM);
#pragma unroll 2
                for (int s = 2; s < K_CH; s += 2) { PSTEP(s, xpA) PSTEP(s + 1, xpB) }
            } else {
                const int t0 = p * K_CH;
#pragma unroll 2
                for (int s = 0; s < K_CH; s += 2) { PSTEP(t0 + s, xpA) PSTEP(t0 + s + 1, xpB) }
            }
        }
        if (wid == 1 && p >= 1) {
            const int cp  = p - 1;
            const int buf = cp & 1;
            // pd1 for s=0 (off-chain: ring data only)
            Frag hB; hB.u = *reinterpret_cast<const uint4*>(&ring[buf][0][l][0]);
            f32x4 pd1a = __builtin_amdgcn_mfma_f32_16x16x32_f16(wT0[0], hB.v, bC[0], 0,0,0);
            f32x4 pd1b = __builtin_amdgcn_mfma_f32_16x16x32_f16(wT0[1], hB.v, bC[1], 0,0,0);
#pragma unroll 2
            for (int s = 0; s < K_CH; ++s) {
                // chain: ONE mfma + tanh + pack
                f32x4 D1a = __builtin_amdgcn_mfma_f32_16x16x32_f16(wT1[0], h2f.v, pd1a, 0,0,0);
                f32x4 D1b = __builtin_amdgcn_mfma_f32_16x16x32_f16(wT1[1], h2f.v, pd1b, 0,0,0);
                // off-chain: prefetch next pd1 (clamped at chunk end; re-done at next top)
                const int sn = (s + 1 < K_CH) ? s + 1 : s;
                hB.u = *reinterpret_cast<const uint4*>(&ring[buf][sn][l][0]);
                pd1a = __builtin_amdgcn_mfma_f32_16x16x32_f16(wT0[0], hB.v, bC[0], 0,0,0);
                pd1b = __builtin_amdgcn_mfma_f32_16x16x32_f16(wT0[1], hB.v, bC[1], 0,0,0);
                h20 = tanh_s(D1a[0]); h21 = tanh_s(D1a[1]);
                h22 = tanh_s(D1a[2]); h23 = tanh_s(D1a[3]);
                h24 = tanh_s(D1b[0]); h25 = tanh_s(D1b[1]);
                h26 = tanh_s(D1b[2]); h27 = tanh_s(D1b[3]);
                h2f.v = pack8(h20, h21, h22, h23, h24, h25, h26, h27);
            }
        }
        __syncthreads();
    }
#undef PSTEP

    // ---- FC epilogue from wave1's h2(T-1) registers ----
    if (wid == 1) {
        float4 fw0 = *reinterpret_cast<const float4*>(fcw + 4 * g);
        float4 fw1 = *reinterpret_cast<const float4*>(fcw + 16 + 4 * g);
        float part = fw0.x * h20 + fw0.y * h21 + fw0.z * h22 + fw0.w * h23
                   + fw1.x * h24 + fw1.y * h25 + fw1.z * h26 + fw1.w * h27;
        part += __shfl_xor(part, 16, 64);
        part += __shfl_xor(part, 32, 64);
        if (l < COLS) out[rowbase + l] = part + fcb[0];
    }
}

extern "C" void kernel_launch(void* const* d_in, const int* in_sizes, int n_in,
                              void* d_out, int out_size, void* d_ws, size_t ws_size,
                              hipStream_t stream) {
    const float* x    = (const float*)d_in[0];
    const float* Wih0 = (const float*)d_in[1];
    const float* Whh0 = (const float*)d_in[2];
    const float* bih0 = (const float*)d_in[3];
    const float* bhh0 = (const float*)d_in[4];
    const float* Wih1 = (const float*)d_in[5];
    const float* Whh1 = (const float*)d_in[6];
    const float* bih1 = (const float*)d_in[7];
    const float* bhh1 = (const float*)d_in[8];
    const float* fcw  = (const float*)d_in[9];
    const float* fcb  = (const float*)d_in[10];
    float* out = (float*)d_out;

    dim3 grid(B_DIM / COLS);   // 512 blocks x 2 waves = 1024 waves = 1/SIMD
    rnn2_pc2_kernel<<<grid, 128, 0, stream>>>(x, Wih0, Whh0, bih0, bhh0,
                                              Wih1, Whh1, bih1, bhh1,
                                              fcw, fcb, out);
}

// Round 19
// 91.924 us; speedup vs baseline: 1.8765x; 1.0664x over previous
//
#include <hip/hip_runtime.h>

#define T_DIM 512
#define I_DIM 16
#define B_DIM 4096
#define K_CH 32            // steps per chunk (ring = 64 KB, 2 blocks/CU)
#define COLS 8             // real batch cols per block (16-wide tile, 2x dup)
#define SCL 2.885390081777927f   // 2*log2(e), folded into weights/biases

typedef _Float16 f16x8 __attribute__((ext_vector_type(8)));
typedef float f32x4 __attribute__((ext_vector_type(4)));
typedef __fp16 hf2v __attribute__((ext_vector_type(2)));

union Frag { f16x8 v; __fp16 e[8]; uint4 u; };

// pre-activation already scaled by 2*log2(e): tanh = 1 - 2/(exp2(u)+1)
__device__ __forceinline__ float tanh_s(float u) {
    float e = __builtin_amdgcn_exp2f(u);
    return fmaf(-2.f, __builtin_amdgcn_rcpf(e + 1.f), 1.f);
}

__device__ __forceinline__ f16x8 pack8(float a0, float a1, float a2, float a3,
                                       float b0, float b1, float b2, float b3) {
    Frag f;
    hf2v p0 = __builtin_amdgcn_cvt_pkrtz(a0, a1);
    hf2v p1 = __builtin_amdgcn_cvt_pkrtz(a2, a3);
    hf2v p2 = __builtin_amdgcn_cvt_pkrtz(b0, b1);
    hf2v p3 = __builtin_amdgcn_cvt_pkrtz(b2, b3);
    f.e[0] = p0[0]; f.e[1] = p0[1]; f.e[2] = p1[0]; f.e[3] = p1[1];
    f.e[4] = p2[0]; f.e[5] = p2[1]; f.e[6] = p3[0]; f.e[7] = p3[1];
    return f.v;
}
__device__ __forceinline__ f16x8 tanhpack_s(f32x4 a, f32x4 b) {
    return pack8(tanh_s(a[0]), tanh_s(a[1]), tanh_s(a[2]), tanh_s(a[3]),
                 tanh_s(b[0]), tanh_s(b[1]), tanh_s(b[2]), tanh_s(b[3]));
}
// q-permuted A-frag loads (q(8g+j) = 4g+j | 16+4g+j-4), verified r15-r18,
// tanh scale folded in.
__device__ __forceinline__ f16x8 loadWq32s(const float* W, int row, int g) {
    float4 a = *reinterpret_cast<const float4*>(W + row * 32 + 4 * g);
    float4 b = *reinterpret_cast<const float4*>(W + row * 32 + 16 + 4 * g);
    return pack8(a.x*SCL, a.y*SCL, a.z*SCL, a.w*SCL, b.x*SCL, b.y*SCL, b.z*SCL, b.w*SCL);
}
__device__ __forceinline__ f16x8 loadWq16s(const float* W, int row, int g) {
    float4 a = *reinterpret_cast<const float4*>(W + row * 16 + 4 * g);
    return pack8(a.x*SCL, a.y*SCL, a.z*SCL, a.w*SCL, 0.f, 0.f, 0.f, 0.f);
}

// r18 producer-consumer structure + 8-deep x prefetch ring: a load issued at
// step t is consumed at t+8 (>= 1200cy at any plausible wall) so HBM latency
// (~900cy) never lands on the recurrence chain.
__global__ void __launch_bounds__(128)
rnn2_pc8_kernel(const float* __restrict__ x,
                const float* __restrict__ Wih0, const float* __restrict__ Whh0,
                const float* __restrict__ bih0, const float* __restrict__ bhh0,
                const float* __restrict__ Wih1, const float* __restrict__ Whh1,
                const float* __restrict__ bih1, const float* __restrict__ bhh1,
                const float* __restrict__ fcw, const float* __restrict__ fcb,
                float* __restrict__ out)
{
    const int tid = threadIdx.x;
    const int l   = tid & 63;
    const int wid = tid >> 6;
    const int c   = l & 15;
    const int g   = l >> 4;
    const int rowbase = blockIdx.x * COLS;

    __shared__ __fp16 ring[2][K_CH][64][8];   // 64 KB

    f16x8 wT0[2], wT1[2];
    f32x4 bC[2];
    Frag  h1f;
    f32x4 Xacc[2];
    float4 xp0, xp1, xp2, xp3, xp4, xp5, xp6, xp7;
    const float* xlane = nullptr;
    float h20=0.f,h21=0.f,h22=0.f,h23=0.f,h24=0.f,h25=0.f,h26=0.f,h27=0.f;
    Frag h2f; h2f.u = make_uint4(0u, 0u, 0u, 0u);   // h2(-1) = 0

    if (wid == 0) {
#pragma unroll
        for (int tt = 0; tt < 2; ++tt) {
            const int row = c + 16 * tt;
            wT0[tt] = loadWq32s(Whh0, row, g);
            wT1[tt] = loadWq16s(Wih0, row, g);
            const int r0 = 4 * g + 16 * tt;
            float4 bi = *reinterpret_cast<const float4*>(bih0 + r0);
            float4 bh = *reinterpret_cast<const float4*>(bhh0 + r0);
            bC[tt][0] = (bi.x + bh.x) * SCL; bC[tt][1] = (bi.y + bh.y) * SCL;
            bC[tt][2] = (bi.z + bh.z) * SCL; bC[tt][3] = (bi.w + bh.w) * SCL;
        }
        const size_t xcol = rowbase + (c & (COLS - 1));
        xlane = x + xcol * (size_t)(T_DIM * I_DIM) + 4 * g;
    } else {
#pragma unroll
        for (int tt = 0; tt < 2; ++tt) {
            const int row = c + 16 * tt;
            wT0[tt] = loadWq32s(Wih1, row, g);
            wT1[tt] = loadWq32s(Whh1, row, g);
            const int r0 = 4 * g + 16 * tt;
            float4 bi = *reinterpret_cast<const float4*>(bih1 + r0);
            float4 bh = *reinterpret_cast<const float4*>(bhh1 + r0);
            bC[tt][0] = (bi.x + bh.x) * SCL; bC[tt][1] = (bi.y + bh.y) * SCL;
            bC[tt][2] = (bi.z + bh.z) * SCL; bC[tt][3] = (bi.w + bh.w) * SCL;
        }
    }

// PSTEP(t, P): P holds x(t+1); consume it, reload P = x(t+9) (used at t+8)
#define PSTEP(t, P)                                                                         \
    {                                                                                       \
        f32x4 D0a = __builtin_amdgcn_mfma_f32_16x16x32_f16(wT0[0], h1f.v, Xacc[0], 0,0,0);  \
        f32x4 D0b = __builtin_amdgcn_mfma_f32_16x16x32_f16(wT0[1], h1f.v, Xacc[1], 0,0,0);  \
        Frag xf; xf.v = pack8((P).x, (P).y, (P).z, (P).w, 0.f, 0.f, 0.f, 0.f);              \
        const int tn = ((t) + 9 < T_DIM) ? (t) + 9 : (T_DIM - 1);                           \
        (P) = *reinterpret_cast<const float4*>(xlane + (size_t)tn * I_DIM);                 \
        h1f.v = tanhpack_s(D0a, D0b);                                                       \
        *reinterpret_cast<uint4*>(&ring[((t) / K_CH) & 1][(t) & (K_CH - 1)][l][0]) = h1f.u; \
        Xacc[0] = __builtin_amdgcn_mfma_f32_16x16x32_f16(wT1[0], xf.v, bC[0], 0,0,0);       \
        Xacc[1] = __builtin_amdgcn_mfma_f32_16x16x32_f16(wT1[1], xf.v, bC[1], 0,0,0);       \
    }

#pragma unroll 1
    for (int p = 0; p <= T_DIM / K_CH; ++p) {
        if (wid == 0 && p < T_DIM / K_CH) {
            if (p == 0) {
                // ---- serial prologue: h1(0..7) with inline x-folds ----
                {
                    float4 xq = *reinterpret_cast<const float4*>(xlane + 0 * I_DIM);
                    Frag xg; xg.v = pack8(xq.x, xq.y, xq.z, xq.w, 0.f, 0.f, 0.f, 0.f);
                    f32x4 A0 = __builtin_amdgcn_mfma_f32_16x16x32_f16(wT1[0], xg.v, bC[0], 0,0,0);
                    f32x4 A1 = __builtin_amdgcn_mfma_f32_16x16x32_f16(wT1[1], xg.v, bC[1], 0,0,0);
                    h1f.v = tanhpack_s(A0, A1);
                    *reinterpret_cast<uint4*>(&ring[0][0][l][0]) = h1f.u;
                }
#pragma unroll
                for (int t = 1; t < 8; ++t) {
                    float4 xq = *reinterpret_cast<const float4*>(xlane + (size_t)t * I_DIM);
                    Frag xg; xg.v = pack8(xq.x, xq.y, xq.z, xq.w, 0.f, 0.f, 0.f, 0.f);
                    f32x4 X0 = __builtin_amdgcn_mfma_f32_16x16x32_f16(wT1[0], xg.v, bC[0], 0,0,0);
                    f32x4 X1 = __builtin_amdgcn_mfma_f32_16x16x32_f16(wT1[1], xg.v, bC[1], 0,0,0);
                    f32x4 D0 = __builtin_amdgcn_mfma_f32_16x16x32_f16(wT0[0], h1f.v, X0, 0,0,0);
                    f32x4 D1 = __builtin_amdgcn_mfma_f32_16x16x32_f16(wT0[1], h1f.v, X1, 0,0,0);
                    h1f.v = tanhpack_s(D0, D1);
                    *reinterpret_cast<uint4*>(&ring[0][t][l][0]) = h1f.u;
                }
                // Xacc = fold x(8); fill 8-deep ring with x(9..16)
                {
                    float4 xq = *reinterpret_cast<const float4*>(xlane + 8 * I_DIM);
                    Frag xg; xg.v = pack8(xq.x, xq.y, xq.z, xq.w, 0.f, 0.f, 0.f, 0.f);
                    Xacc[0] = __builtin_amdgcn_mfma_f32_16x16x32_f16(wT1[0], xg.v, bC[0], 0,0,0);
                    Xacc[1] = __builtin_amdgcn_mfma_f32_16x16x32_f16(wT1[1], xg.v, bC[1], 0,0,0);
                }
                xp0 = *reinterpret_cast<const float4*>(xlane +  9 * I_DIM);
                xp1 = *reinterpret_cast<const float4*>(xlane + 10 * I_DIM);
                xp2 = *reinterpret_cast<const float4*>(xlane + 11 * I_DIM);
                xp3 = *reinterpret_cast<const float4*>(xlane + 12 * I_DIM);
                xp4 = *reinterpret_cast<const float4*>(xlane + 13 * I_DIM);
                xp5 = *reinterpret_cast<const float4*>(xlane + 14 * I_DIM);
                xp6 = *reinterpret_cast<const float4*>(xlane + 15 * I_DIM);
                xp7 = *reinterpret_cast<const float4*>(xlane + 16 * I_DIM);
                // steps 8..31: 24 = 3 groups of 8
#pragma unroll 1
                for (int sgrp = 8; sgrp < K_CH; sgrp += 8) {
                    PSTEP(sgrp + 0, xp0) PSTEP(sgrp + 1, xp1)
                    PSTEP(sgrp + 2, xp2) PSTEP(sgrp + 3, xp3)
                    PSTEP(sgrp + 4, xp4) PSTEP(sgrp + 5, xp5)
                    PSTEP(sgrp + 6, xp6) PSTEP(sgrp + 7, xp7)
                }
            } else {
                const int t0 = p * K_CH;
#pragma unroll 1
                for (int sgrp = 0; sgrp < K_CH; sgrp += 8) {
                    PSTEP(t0 + sgrp + 0, xp0) PSTEP(t0 + sgrp + 1, xp1)
                    PSTEP(t0 + sgrp + 2, xp2) PSTEP(t0 + sgrp + 3, xp3)
                    PSTEP(t0 + sgrp + 4, xp4) PSTEP(t0 + sgrp + 5, xp5)
                    PSTEP(t0 + sgrp + 6, xp6) PSTEP(t0 + sgrp + 7, xp7)
                }
            }
        }
        if (wid == 1 && p >= 1) {
            const int cp  = p - 1;
            const int buf = cp & 1;
            Frag hB; hB.u = *reinterpret_cast<const uint4*>(&ring[buf][0][l][0]);
            f32x4 pd1a = __builtin_amdgcn_mfma_f32_16x16x32_f16(wT0[0], hB.v, bC[0], 0,0,0);
            f32x4 pd1b = __builtin_amdgcn_mfma_f32_16x16x32_f16(wT0[1], hB.v, bC[1], 0,0,0);
#pragma unroll 2
            for (int s = 0; s < K_CH; ++s) {
                f32x4 D1a = __builtin_amdgcn_mfma_f32_16x16x32_f16(wT1[0], h2f.v, pd1a, 0,0,0);
                f32x4 D1b = __builtin_amdgcn_mfma_f32_16x16x32_f16(wT1[1], h2f.v, pd1b, 0,0,0);
                const int sn = (s + 1 < K_CH) ? s + 1 : s;
                hB.u = *reinterpret_cast<const uint4*>(&ring[buf][sn][l][0]);
                pd1a = __builtin_amdgcn_mfma_f32_16x16x32_f16(wT0[0], hB.v, bC[0], 0,0,0);
                pd1b = __builtin_amdgcn_mfma_f32_16x16x32_f16(wT0[1], hB.v, bC[1], 0,0,0);
                h20 = tanh_s(D1a[0]); h21 = tanh_s(D1a[1]);
                h22 = tanh_s(D1a[2]); h23 = tanh_s(D1a[3]);
                h24 = tanh_s(D1b[0]); h25 = tanh_s(D1b[1]);
                h26 = tanh_s(D1b[2]); h27 = tanh_s(D1b[3]);
                h2f.v = pack8(h20, h21, h22, h23, h24, h25, h26, h27);
            }
        }
        __syncthreads();
    }
#undef PSTEP

    // ---- FC epilogue from wave1's h2(T-1) registers ----
    if (wid == 1) {
        float4 fw0 = *reinterpret_cast<const float4*>(fcw + 4 * g);
        float4 fw1 = *reinterpret_cast<const float4*>(fcw + 16 + 4 * g);
        float part = fw0.x * h20 + fw0.y * h21 + fw0.z * h22 + fw0.w * h23
                   + fw1.x * h24 + fw1.y * h25 + fw1.z * h26 + fw1.w * h27;
        part += __shfl_xor(part, 16, 64);
        part += __shfl_xor(part, 32, 64);
        if (l < COLS) out[rowbase + l] = part + fcb[0];
    }
}

extern "C" void kernel_launch(void* const* d_in, const int* in_sizes, int n_in,
                              void* d_out, int out_size, void* d_ws, size_t ws_size,
                              hipStream_t stream) {
    const float* x    = (const float*)d_in[0];
    const float* Wih0 = (const float*)d_in[1];
    const float* Whh0 = (const float*)d_in[2];
    const float* bih0 = (const float*)d_in[3];
    const float* bhh0 = (const float*)d_in[4];
    const float* Wih1 = (const float*)d_in[5];
    const float* Whh1 = (const float*)d_in[6];
    const float* bih1 = (const float*)d_in[7];
    const float* bhh1 = (const float*)d_in[8];
    const float* fcw  = (const float*)d_in[9];
    const float* fcb  = (const float*)d_in[10];
    float* out = (float*)d_out;

    dim3 grid(B_DIM / COLS);   // 512 blocks x 2 waves = 1024 waves
    rnn2_pc8_kernel<<<grid, 128, 0, stream>>>(x, Wih0, Whh0, bih0, bhh0,
                                              Wih1, Whh1, bih1, bhh1,
                                              fcw, fcb, out);
}